// Round 1
// baseline (160.608 us; speedup 1.0000x reference)
//
#include <hip/hip_runtime.h>
#include <hip/hip_bf16.h>

typedef __attribute__((ext_vector_type(8))) short s16x8;
typedef __attribute__((ext_vector_type(4))) float f32x4;
typedef __attribute__((ext_vector_type(8))) unsigned short u16x8;
typedef __attribute__((ext_vector_type(4))) unsigned short u16x4;

static __device__ __forceinline__ unsigned short f2bf(float f) {
  unsigned int u = __float_as_uint(f);
  unsigned int r = u + 0x7fffu + ((u >> 16) & 1u);
  return (unsigned short)(r >> 16);
}

// ---------------- small kernels ----------------

// proj_w fp32 (768*256) -> bf16, layout unchanged (already (N=768, K=256) row-major)
__global__ void k_cvt(const float* __restrict__ in, unsigned short* __restrict__ o) {
  int i = blockIdx.x * 256 + threadIdx.x;  // 192*256 = 49152 float4s
  float4 v = reinterpret_cast<const float4*>(in)[i];
  u16x4 pk = { f2bf(v.x), f2bf(v.y), f2bf(v.z), f2bf(v.w) };
  reinterpret_cast<u16x4*>(o)[i] = pk;
}

// ctx_w (768x768) transpose -> cwT[f][e] = ctx_w[e][f]
__global__ void k_transpose768(const float* __restrict__ in, float* __restrict__ out) {
  __shared__ float tile[32][33];
  int bx = blockIdx.x % 24, by = blockIdx.x / 24;
  int tx = threadIdx.x & 31, ty = threadIdx.x >> 5;
#pragma unroll
  for (int k = 0; k < 4; ++k)
    tile[ty + 8 * k][tx] = in[(size_t)(by * 32 + ty + 8 * k) * 768 + bx * 32 + tx];
  __syncthreads();
#pragma unroll
  for (int k = 0; k < 4; ++k)
    out[(size_t)(bx * 32 + ty + 8 * k) * 768 + by * 32 + tx] = tile[tx][ty + 8 * k];
}

// avg_patch[bc][k] = mean over 14x14 patches of x[bc][hp*16+p][wp*16+q], k = p*16+q
__global__ void k_avgpatch(const float* __restrict__ x, float* __restrict__ avg) {
  int bc = blockIdx.x;           // 256
  int k = threadIdx.x;           // 256
  int p = k >> 4, q = k & 15;
  const float* base = x + (size_t)bc * 224 * 224;
  float s = 0.f;
  for (int hp = 0; hp < 14; ++hp) {
    const float* row = base + (hp * 16 + p) * 224 + q;
#pragma unroll
    for (int wp = 0; wp < 14; ++wp) s += row[wp * 16];
  }
  avg[bc * 256 + k] = s * (1.0f / 196.0f);
}

// seg_patch[s][k] = mean over bc with seg[bc]==s of avg_patch[bc][k] (cnt clamped to 1)
__global__ void k_segpatch(const float* __restrict__ avg, const int* __restrict__ seg,
                           float* __restrict__ sp) {
  __shared__ int ssg[256];
  int s = blockIdx.x, k = threadIdx.x;
  ssg[k] = seg[k];
  __syncthreads();
  float sum = 0.f; int c = 0;
  for (int bc = 0; bc < 256; ++bc)
    if (ssg[bc] == s) { sum += avg[bc * 256 + k]; ++c; }
  sp[s * 256 + k] = sum / (float)(c > 0 ? c : 1);
}

// means[s][e] = dot(seg_patch[s], proj_w[e]) + proj_b[e]   (fp32)
__global__ void k_means(const float* __restrict__ sp, const float* __restrict__ pw,
                        const float* __restrict__ pb, float* __restrict__ means) {
  __shared__ float s[256];
  int sg = blockIdx.x, e = threadIdx.x;  // 32 blocks, 768 threads
  if (e < 256) s[e] = sp[sg * 256 + e];
  __syncthreads();
  const float4* w = reinterpret_cast<const float4*>(pw + (size_t)e * 256);
  float acc = 0.f;
#pragma unroll 8
  for (int k = 0; k < 64; ++k) {
    float4 v = w[k];
    acc += v.x * s[k * 4] + v.y * s[k * 4 + 1] + v.z * s[k * 4 + 2] + v.w * s[k * 4 + 3];
  }
  means[sg * 768 + e] = acc + pb[e];
}

// addv[s][e] = sum_f means[s][f] * ctx_w[e][f] + ctx_b[e] + proj_b[e]   (uses cwT, coalesced)
__global__ void k_ctx(const float* __restrict__ means, const float* __restrict__ cwT,
                      const float* __restrict__ cb, const float* __restrict__ pb,
                      float* __restrict__ addv) {
  __shared__ float m[768];
  int s = blockIdx.x, e = threadIdx.x;   // 32 blocks, 768 threads
  m[e] = means[s * 768 + e];
  __syncthreads();
  float acc = 0.f;
#pragma unroll 8
  for (int f = 0; f < 768; ++f) acc += m[f] * cwT[(size_t)f * 768 + e];
  addv[s * 768 + e] = acc + cb[e] + pb[e];
}

// ---------------- main GEMM ----------------
// C[M=50176][N=768] = patches(M,256) x proj_w^T(256,768), epilogue += addv[seg[M/196]][n]
// BM=128, BN=128, 4 waves (2x2, 64x64 each), mfma 16x16x32 bf16, K-steps of 32.
__global__ __launch_bounds__(256) void k_gemm(
    const float* __restrict__ x, const unsigned short* __restrict__ wbf,
    const float* __restrict__ addv, const int* __restrict__ seg,
    float* __restrict__ out) {
  __shared__ unsigned short Al[128][40];  // +8 pad: 80B stride, 2-way max conflict
  __shared__ unsigned short Bl[128][40];

  // XCD-grouped mapping: bid%8 = XCD; each XCD owns a contiguous mb range so the
  // 6 nb-blocks sharing an A-panel hit the same L2. 2352 = 8 * 49 * 6.
  int bid = blockIdx.x;
  int xcd = bid & 7, local = bid >> 3;
  int mb = xcd * 49 + local / 6;
  int nb = local - (local / 6) * 6;
  int m0 = mb << 7, n0 = nb << 7;

  int t = threadIdx.x;
  int wave = t >> 6, lane = t & 63;
  int wm = (wave >> 1) << 6, wn = (wave & 1) << 6;
  int lr = lane & 15, lk = (lane >> 4) << 3;

  // A staging: thread t owns patch m0+(t>>1), half (t&1); per k-step it loads one
  // 16-float patch row (p = 2*ks + half) and writes 16 bf16 to Al[m][half*16..].
  int mstage = m0 + (t >> 1);
  int halfA = t & 1;
  int bc = mstage / 196;
  int pij = mstage - bc * 196;
  int hp = pij / 14;
  int wp = pij - hp * 14;
  const float* xbase = x + ((size_t)bc * 224 + hp * 16 + halfA) * 224 + wp * 16;

  const unsigned short* bsrc = wbf + (size_t)(n0 + (t >> 1)) * 256 + halfA * 16;
  unsigned short* adst = &Al[t >> 1][halfA * 16];
  unsigned short* bdst = &Bl[t >> 1][halfA * 16];

  f32x4 acc[4][4] = {};

  for (int ks = 0; ks < 8; ++ks) {
    __syncthreads();
    // stage B tile (128 n-rows x 32 k) from bf16 proj_w
    *(u16x8*)bdst       = *(const u16x8*)(bsrc + ks * 32);
    *(u16x8*)(bdst + 8) = *(const u16x8*)(bsrc + ks * 32 + 8);
    // stage A tile (128 patches x 32 k), fp32 -> bf16
    {
      const float4* src = reinterpret_cast<const float4*>(xbase + ks * 448);
      float4 v0 = src[0], v1 = src[1], v2 = src[2], v3 = src[3];
      u16x8 p0 = { f2bf(v0.x), f2bf(v0.y), f2bf(v0.z), f2bf(v0.w),
                   f2bf(v1.x), f2bf(v1.y), f2bf(v1.z), f2bf(v1.w) };
      u16x8 p1 = { f2bf(v2.x), f2bf(v2.y), f2bf(v2.z), f2bf(v2.w),
                   f2bf(v3.x), f2bf(v3.y), f2bf(v3.z), f2bf(v3.w) };
      *(u16x8*)adst = p0;
      *(u16x8*)(adst + 8) = p1;
    }
    __syncthreads();

    s16x8 af[4], bfv[4];
#pragma unroll
    for (int i = 0; i < 4; ++i)
      af[i] = *(const s16x8*)&Al[wm + i * 16 + lr][lk];
#pragma unroll
    for (int j = 0; j < 4; ++j)
      bfv[j] = *(const s16x8*)&Bl[wn + j * 16 + lr][lk];
#pragma unroll
    for (int i = 0; i < 4; ++i)
#pragma unroll
      for (int j = 0; j < 4; ++j)
        acc[i][j] = __builtin_amdgcn_mfma_f32_16x16x32_bf16(af[i], bfv[j], acc[i][j], 0, 0, 0);
  }

  // epilogue: out[M][n] = acc + addv[seg[M/196]][n]
#pragma unroll
  for (int i = 0; i < 4; ++i) {
    int mloc = m0 + wm + i * 16 + ((lane >> 4) << 2);
#pragma unroll
    for (int r = 0; r < 4; ++r) {
      int M = mloc + r;
      int sgi = seg[M / 196];
      const float* av = addv + (size_t)sgi * 768 + n0 + wn + lr;
      float* orow = out + (size_t)M * 768 + n0 + wn + lr;
#pragma unroll
      for (int j = 0; j < 4; ++j)
        orow[j * 16] = acc[i][j][r] + av[j * 16];
    }
  }
}

// ---------------- launch ----------------

extern "C" void kernel_launch(void* const* d_in, const int* in_sizes, int n_in,
                              void* d_out, int out_size, void* d_ws, size_t ws_size,
                              hipStream_t stream) {
  (void)in_sizes; (void)n_in; (void)out_size; (void)ws_size;
  const float* x  = (const float*)d_in[0];
  const int*   sg = (const int*)d_in[1];
  const float* pw = (const float*)d_in[2];
  const float* pb = (const float*)d_in[3];
  const float* cw = (const float*)d_in[4];
  const float* cb = (const float*)d_in[5];
  float* out = (float*)d_out;

  char* ws = (char*)d_ws;
  unsigned short* pwbf = (unsigned short*)ws;          // 768*256*2   = 393216
  float* avgp  = (float*)(ws + 393216);                // 256*256*4   = 262144
  float* segp  = (float*)(ws + 655360);                // 32*256*4    = 32768
  float* means = (float*)(ws + 688128);                // 32*768*4    = 98304
  float* cwT   = (float*)(ws + 786432);                // 768*768*4   = 2359296
  float* addv  = (float*)(ws + 3145728);               // 32*768*4    = 98304
                                                       // total 3244032 bytes

  k_cvt<<<192, 256, 0, stream>>>(pw, pwbf);
  k_transpose768<<<576, 256, 0, stream>>>(cw, cwT);
  k_avgpatch<<<256, 256, 0, stream>>>(x, avgp);
  k_segpatch<<<32, 256, 0, stream>>>(avgp, sg, segp);
  k_means<<<32, 768, 0, stream>>>(segp, pw, pb, means);
  k_ctx<<<32, 768, 0, stream>>>(means, cwT, cb, pb, addv);
  k_gemm<<<2352, 256, 0, stream>>>(x, pwbf, addv, sg, out);
}